// Round 1
// baseline (745.322 us; speedup 1.0000x reference)
//
#include <hip/hip_runtime.h>
#include <math.h>

// Problem constants (match reference)
constexpr int N = 10000;   // nodes
constexpr int E = 50000;   // edges
constexpr int D = 32;      // dim
constexpr int H = 4;       // heads
// HEAD_DIM = 8

// ---------------------------------------------------------------------------
// Kernel 1: per-edge hypernetwork matvecs + logits + exp + denom atomics.
// One block (256 threads) per edge. Thread t: hd = t>>3 (0..31 = h*8+d),
// seg = t&7 (i-range seg*4..seg*4+3). Each thread does ONE float4 load per
// weight tensor -> fully coalesced 4KB/tensor/block streaming.
// ---------------------------------------------------------------------------
__global__ __launch_bounds__(256) void edge_kernel(
    const float* __restrict__ in_feat,
    const int*   __restrict__ src, const int* __restrict__ dst,
    const float* __restrict__ skw, const float* __restrict__ dkw,
    const float* __restrict__ skb, const float* __restrict__ dkb,
    const float* __restrict__ svw, const float* __restrict__ dvw,
    const float* __restrict__ svb, const float* __restrict__ dvb,
    const float* __restrict__ query,
    float* __restrict__ key_feat, float* __restrict__ value_feat,
    float* __restrict__ ex_out,   // attn slot of d_out, holds exp(logit) for now
    float* __restrict__ denom)    // ws, zero-initialized, N*H
{
    const int e   = blockIdx.x;
    const int tid = threadIdx.x;
    const int hd  = tid >> 3;   // 0..31
    const int seg = tid & 7;    // 0..7
    const int s = src[e];
    const int d = dst[e];

    const float4 u4 = *reinterpret_cast<const float4*>(in_feat + s * D + seg * 4);
    const float4 v4 = *reinterpret_cast<const float4*>(in_feat + d * D + seg * 4);

    // flat weight offset: (e*32 + hd)*32 + seg*4 == e*1024 + tid*4
    const size_t woff = (size_t)e * 1024 + (size_t)tid * 4;

    float4 wa = *reinterpret_cast<const float4*>(skw + woff);
    float4 wb = *reinterpret_cast<const float4*>(dkw + woff);
    float pk = wa.x * u4.x + wa.y * u4.y + wa.z * u4.z + wa.w * u4.w
             + wb.x * v4.x + wb.y * v4.y + wb.z * v4.z + wb.w * v4.w;
    wa = *reinterpret_cast<const float4*>(svw + woff);
    wb = *reinterpret_cast<const float4*>(dvw + woff);
    float pv = wa.x * u4.x + wa.y * u4.y + wa.z * u4.z + wa.w * u4.w
             + wb.x * v4.x + wb.y * v4.y + wb.z * v4.z + wb.w * v4.w;

    // reduce over seg (lanes grouped in 8s within the wave)
    #pragma unroll
    for (int off = 1; off < 8; off <<= 1) {
        pk += __shfl_xor(pk, off);
        pv += __shfl_xor(pv, off);
    }

    const int bi = e * D + hd;
    const float Kv = pk + skb[bi] + dkb[bi];
    const float Vv = pv + svb[bi] + dvb[bi];
    if (seg == 0) {
        key_feat[bi]   = Kv;
        value_feat[bi] = Vv;
    }

    // logit[h] = sum_d K[h,d]*q[h,d]. Within wave h: d = lane>>3, all 8 lanes
    // of a d-group hold identical K. Reducing over lane bits 3..5 sums each d
    // exactly once per lane -> logit on every lane of wave h.
    float c = Kv * query[d * D + hd];
    #pragma unroll
    for (int off = 8; off < 64; off <<= 1) c += __shfl_xor(c, off);

    if ((tid & 63) == 0) {
        const int h = tid >> 6;  // wave index == head
        // softmax is shift-invariant; logits ~N(0,~1), expf in f32 is safe
        const float exv = expf(c);
        ex_out[e * H + h] = exv;
        atomicAdd(denom + d * H + h, exv);
    }
}

// ---------------------------------------------------------------------------
// Kernel 2: attn = ex/denom (in place), scatter attn*V into agg.
// ---------------------------------------------------------------------------
__global__ __launch_bounds__(256) void attn_kernel(
    const int*   __restrict__ dst,
    const float* __restrict__ value_feat,
    const float* __restrict__ denom,
    float* __restrict__ attn,   // holds ex on entry, attn on exit
    float* __restrict__ agg)    // ws, zero-initialized, N*D
{
    const int idx = blockIdx.x * 256 + threadIdx.x;
    if (idx >= E * H) return;
    const int e = idx >> 2;
    const int h = idx & 3;
    const int d = dst[e];
    const float a = attn[idx] / denom[d * H + h];
    attn[idx] = a;
    const float* vp = value_feat + e * D + h * 8;
    float*       ap = agg + d * D + h * 8;
    #pragma unroll
    for (int j = 0; j < 8; ++j) atomicAdd(ap + j, vp[j] * a);
}

// ---------------------------------------------------------------------------
// Kernel 3: per-node dynamic linear + relu + residual + layernorm.
// One wave per node (4 nodes / 256-thread block). lane: o = lane>>1,
// i-half = lane&1 covers i in [half*16, half*16+16).
// ---------------------------------------------------------------------------
__global__ __launch_bounds__(256) void node_kernel(
    const float* __restrict__ in_feat,
    const float* __restrict__ node_w,
    const float* __restrict__ node_b,
    const float* __restrict__ ln_w, const float* __restrict__ ln_b,
    const float* __restrict__ agg,
    float* __restrict__ out)
{
    const int wave = threadIdx.x >> 6;
    const int lane = threadIdx.x & 63;
    const int n = blockIdx.x * 4 + wave;
    if (n >= N) return;
    const int o    = lane >> 1;
    const int half = lane & 1;

    const float* w = node_w + (size_t)n * 1024 + o * 32 + half * 16;
    const float* g = agg + n * D + half * 16;
    float p = 0.f;
    #pragma unroll
    for (int j = 0; j < 16; j += 4) {
        const float4 wv = *reinterpret_cast<const float4*>(w + j);
        const float4 gv = *reinterpret_cast<const float4*>(g + j);
        p += wv.x * gv.x + wv.y * gv.y + wv.z * gv.z + wv.w * gv.w;
    }
    p += __shfl_xor(p, 1);  // full dot on both lanes of the pair

    const float r = in_feat[n * D + o] + fmaxf(p + node_b[n * D + o], 0.0f);

    // LayerNorm over the 32 o's: reduce over lane bits 1..5 — the 32 lanes
    // sharing bit0 cover each o exactly once.
    float sum = r, sq = r * r;
    #pragma unroll
    for (int off = 2; off < 64; off <<= 1) {
        sum += __shfl_xor(sum, off);
        sq  += __shfl_xor(sq, off);
    }
    const float mean = sum * (1.0f / 32.0f);
    const float var  = sq * (1.0f / 32.0f) - mean * mean;
    const float y = (r - mean) * rsqrtf(var + 1e-5f) * ln_w[o] + ln_b[o];
    if (half == 0) out[n * D + o] = y;
}

// ---------------------------------------------------------------------------
extern "C" void kernel_launch(void* const* d_in, const int* in_sizes, int n_in,
                              void* d_out, int out_size, void* d_ws, size_t ws_size,
                              hipStream_t stream)
{
    const float* in_feat = (const float*)d_in[0];
    const int*   src     = (const int*)d_in[1];
    const int*   dst     = (const int*)d_in[2];
    const float* skw     = (const float*)d_in[3];
    const float* dkw     = (const float*)d_in[4];
    const float* skb     = (const float*)d_in[5];
    const float* dkb     = (const float*)d_in[6];
    const float* svw     = (const float*)d_in[7];
    const float* dvw     = (const float*)d_in[8];
    const float* svb     = (const float*)d_in[9];
    const float* dvb     = (const float*)d_in[10];
    const float* query   = (const float*)d_in[11];
    const float* node_w  = (const float*)d_in[12];
    const float* node_b  = (const float*)d_in[13];
    const float* ln_w    = (const float*)d_in[14];
    const float* ln_b    = (const float*)d_in[15];

    // d_out layout: out(N*D) | key_feat(E*D) | value_feat(E*D) | attn(E*H)
    float* out        = (float*)d_out;
    float* key_feat   = out + (size_t)N * D;
    float* value_feat = key_feat + (size_t)E * D;
    float* attn       = value_feat + (size_t)E * D;

    // ws layout: denom(N*H) | agg(N*D) — both need zero init (ws is poisoned)
    float* denom = (float*)d_ws;
    float* agg   = denom + N * H;
    hipMemsetAsync(d_ws, 0, (size_t)(N * H + N * D) * sizeof(float), stream);

    edge_kernel<<<E, 256, 0, stream>>>(in_feat, src, dst,
                                       skw, dkw, skb, dkb,
                                       svw, dvw, svb, dvb,
                                       query, key_feat, value_feat,
                                       attn /* ex for now */, denom);

    attn_kernel<<<(E * H + 255) / 256, 256, 0, stream>>>(dst, value_feat,
                                                         denom, attn, agg);

    node_kernel<<<(N + 3) / 4, 256, 0, stream>>>(in_feat, node_w, node_b,
                                                 ln_w, ln_b, agg, out);
}

// Round 2
// 706.995 us; speedup vs baseline: 1.0542x; 1.0542x over previous
//
#include <hip/hip_runtime.h>
#include <math.h>

constexpr int N = 10000;   // nodes
constexpr int E = 50000;   // edges
constexpr int D = 32;      // dim
constexpr int H = 4;       // heads

typedef float v4f __attribute__((ext_vector_type(4)));

// ---------------------------------------------------------------------------
// CSR build: histogram of dst -> exclusive scan -> scatter edge ids.
// ---------------------------------------------------------------------------
__global__ __launch_bounds__(256) void hist_kernel(const int* __restrict__ dst,
                                                   int* __restrict__ counts)
{
    const int e = blockIdx.x * 256 + threadIdx.x;
    if (e < E) atomicAdd(counts + dst[e], 1);
}

__global__ __launch_bounds__(1024) void scan_kernel(const int* __restrict__ counts,
                                                    int* __restrict__ offsets,
                                                    int* __restrict__ cursor)
{
    __shared__ int part[1024];
    const int t = threadIdx.x;
    constexpr int PER = (N + 1023) / 1024;  // 10
    const int base = t * PER;
    int loc[PER];
    int s = 0;
    #pragma unroll
    for (int i = 0; i < PER; ++i) {
        const int c = (base + i < N) ? counts[base + i] : 0;
        loc[i] = s;
        s += c;
    }
    part[t] = s;
    __syncthreads();
    // Hillis-Steele inclusive scan over 1024 partials
    for (int off = 1; off < 1024; off <<= 1) {
        const int v = (t >= off) ? part[t - off] : 0;
        __syncthreads();
        part[t] += v;
        __syncthreads();
    }
    const int pre = (t == 0) ? 0 : part[t - 1];
    #pragma unroll
    for (int i = 0; i < PER; ++i) {
        if (base + i < N) {
            const int o = pre + loc[i];
            offsets[base + i] = o;
            cursor[base + i]  = o;
        }
    }
    if (t == 0) offsets[N] = E;
}

__global__ __launch_bounds__(256) void scatter_kernel(const int* __restrict__ dst,
                                                      int* __restrict__ cursor,
                                                      int* __restrict__ edge_list)
{
    const int e = blockIdx.x * 256 + threadIdx.x;
    if (e < E) {
        const int p = atomicAdd(cursor + dst[e], 1);
        edge_list[p] = e;
    }
}

// ---------------------------------------------------------------------------
// Edge kernel: per-edge hypernetwork matvecs + logit + exp. No atomics.
// One block (256 threads) per edge; thread t: hd = t>>3, seg = t&7; each
// thread does ONE nontemporal float4 load per weight tensor (coalesced,
// read-once streams).
// ---------------------------------------------------------------------------
__global__ __launch_bounds__(256) void edge_kernel(
    const float* __restrict__ in_feat,
    const int*   __restrict__ src, const int* __restrict__ dst,
    const float* __restrict__ skw, const float* __restrict__ dkw,
    const float* __restrict__ skb, const float* __restrict__ dkb,
    const float* __restrict__ svw, const float* __restrict__ dvw,
    const float* __restrict__ svb, const float* __restrict__ dvb,
    const float* __restrict__ query,
    float* __restrict__ key_feat, float* __restrict__ value_feat,
    float* __restrict__ ex_out)   // attn slot of d_out; holds exp(logit)
{
    const int e   = blockIdx.x;
    const int tid = threadIdx.x;
    const int hd  = tid >> 3;   // 0..31
    const int seg = tid & 7;    // 0..7
    const int s = src[e];
    const int d = dst[e];

    const float4 u4 = *reinterpret_cast<const float4*>(in_feat + s * D + seg * 4);
    const float4 v4 = *reinterpret_cast<const float4*>(in_feat + d * D + seg * 4);

    const size_t woff = (size_t)e * 1024 + (size_t)tid * 4;
    const v4f wa = __builtin_nontemporal_load(reinterpret_cast<const v4f*>(skw + woff));
    const v4f wb = __builtin_nontemporal_load(reinterpret_cast<const v4f*>(dkw + woff));
    const v4f wc = __builtin_nontemporal_load(reinterpret_cast<const v4f*>(svw + woff));
    const v4f wd = __builtin_nontemporal_load(reinterpret_cast<const v4f*>(dvw + woff));

    float pk = wa.x * u4.x + wa.y * u4.y + wa.z * u4.z + wa.w * u4.w
             + wb.x * v4.x + wb.y * v4.y + wb.z * v4.z + wb.w * v4.w;
    float pv = wc.x * u4.x + wc.y * u4.y + wc.z * u4.z + wc.w * u4.w
             + wd.x * v4.x + wd.y * v4.y + wd.z * v4.z + wd.w * v4.w;

    #pragma unroll
    for (int off = 1; off < 8; off <<= 1) {
        pk += __shfl_xor(pk, off);
        pv += __shfl_xor(pv, off);
    }

    // only seg==0 lanes need biases / K / V / query
    const int bi = e * D + hd;
    float c = 0.0f;
    if (seg == 0) {
        const float Kv = pk + skb[bi] + dkb[bi];
        const float Vv = pv + svb[bi] + dvb[bi];
        key_feat[bi]   = Kv;
        value_feat[bi] = Vv;
        c = Kv * query[d * D + hd];
    }
    // seg==0 lanes (0,8,..,56) are closed under xor of bits 3..5: lane0 of
    // each wave ends with the full per-head logit.
    #pragma unroll
    for (int off = 8; off < 64; off <<= 1) c += __shfl_xor(c, off);

    if ((tid & 63) == 0) {
        const int h = tid >> 6;  // wave index == head
        // softmax is shift-invariant; logits ~N(0,~1) -> expf safe in f32
        ex_out[e * H + h] = expf(c);
    }
}

// ---------------------------------------------------------------------------
// Fused node kernel: one wave per node (4 nodes / 256-thread block).
// Walk incoming edges (CSR): denom -> normalize+write attn -> aggregate,
// then node matvec + relu + residual + layernorm. No atomics, deterministic.
// ---------------------------------------------------------------------------
__global__ __launch_bounds__(256) void node_kernel(
    const int*   __restrict__ offsets, const int* __restrict__ edge_list,
    const float* __restrict__ in_feat, const float* __restrict__ value_feat,
    const float* __restrict__ node_w,  const float* __restrict__ node_b,
    const float* __restrict__ ln_w,    const float* __restrict__ ln_b,
    float* __restrict__ attn,   // holds exp(logit) on entry, attn on exit
    float* __restrict__ out)
{
    __shared__ float agg_sh[4][33];
    const int wave = threadIdx.x >> 6;
    const int lane = threadIdx.x & 63;
    const int n = blockIdx.x * 4 + wave;   // grid = N/4 exactly (N=10000)

    const int beg = offsets[n];
    const int deg = offsets[n + 1] - beg;

    const int slot = lane >> 2;   // 0..15: edge slot within chunk
    const int hh   = lane & 3;    // head for ex lanes
    const int hd   = lane & 31;   // 0..31: agg element (h*8+d)
    const int h    = hd >> 3;

    // pass 1: softmax denominator per head
    float ds = 0.0f;
    for (int k = slot; k < deg; k += 16)
        ds += attn[edge_list[beg + k] * H + hh];
    #pragma unroll
    for (int off = 4; off < 64; off <<= 1) ds += __shfl_xor(ds, off);
    const float rden = (ds != 0.0f) ? 1.0f / ds : 0.0f;  // lane holds head lane&3

    // pass 2: normalize (same-lane RAW -> safe), write attn, aggregate via
    // in-wave broadcast (no global read-after-cross-lane-write hazard)
    float aggv = 0.0f;
    for (int c = 0; c < deg; c += 16) {
        const int rem = (deg - c < 16) ? (deg - c) : 16;
        int   ee = 0;
        float a  = 0.0f;
        if (slot < rem) {
            ee = edge_list[beg + c + slot];
            const int idx = ee * H + hh;
            a = attn[idx] * rden;
            attn[idx] = a;
        }
        for (int kk = 0; kk < rem; ++kk) {
            const float ak = __shfl(a, kk * 4 + h);
            const int  ek = __shfl(ee, kk * 4);
            aggv += value_feat[ek * D + hd] * ak;
        }
    }
    agg_sh[wave][hd] = aggv;   // lanes 32..63 write duplicates, same value
    __syncthreads();

    // matvec: o = lane>>1, half = lane&1 covers i in [half*16, half*16+16)
    const int o = lane >> 1, half = lane & 1;
    const float* w = node_w + (size_t)n * 1024 + o * 32 + half * 16;
    const float* g = &agg_sh[wave][half * 16];
    float p = 0.0f;
    #pragma unroll
    for (int j = 0; j < 16; j += 4) {
        const float4 wv = *reinterpret_cast<const float4*>(w + j);
        p += wv.x * g[j] + wv.y * g[j + 1] + wv.z * g[j + 2] + wv.w * g[j + 3];
    }
    p += __shfl_xor(p, 1);   // full dot on both lanes of the pair

    const float r = in_feat[n * D + o] + fmaxf(p + node_b[n * D + o], 0.0f);

    float sum = r, sq = r * r;
    #pragma unroll
    for (int off = 2; off < 64; off <<= 1) {
        sum += __shfl_xor(sum, off);
        sq  += __shfl_xor(sq, off);
    }
    const float mean = sum * (1.0f / 32.0f);
    const float var  = sq * (1.0f / 32.0f) - mean * mean;
    const float y = (r - mean) * rsqrtf(var + 1e-5f) * ln_w[o] + ln_b[o];
    if (half == 0) out[n * D + o] = y;
}

// ---------------------------------------------------------------------------
extern "C" void kernel_launch(void* const* d_in, const int* in_sizes, int n_in,
                              void* d_out, int out_size, void* d_ws, size_t ws_size,
                              hipStream_t stream)
{
    const float* in_feat = (const float*)d_in[0];
    const int*   src     = (const int*)d_in[1];
    const int*   dst     = (const int*)d_in[2];
    const float* skw     = (const float*)d_in[3];
    const float* dkw     = (const float*)d_in[4];
    const float* skb     = (const float*)d_in[5];
    const float* dkb     = (const float*)d_in[6];
    const float* svw     = (const float*)d_in[7];
    const float* dvw     = (const float*)d_in[8];
    const float* svb     = (const float*)d_in[9];
    const float* dvb     = (const float*)d_in[10];
    const float* query   = (const float*)d_in[11];
    const float* node_w  = (const float*)d_in[12];
    const float* node_b  = (const float*)d_in[13];
    const float* ln_w    = (const float*)d_in[14];
    const float* ln_b    = (const float*)d_in[15];

    // d_out layout: out(N*D) | key_feat(E*D) | value_feat(E*D) | attn(E*H)
    float* out        = (float*)d_out;
    float* key_feat   = out + (size_t)N * D;
    float* value_feat = key_feat + (size_t)E * D;
    float* attn       = value_feat + (size_t)E * D;

    // ws layout (ints): counts[N] | offsets[N+1] | cursor[N] | edge_list[E]
    int* counts    = (int*)d_ws;
    int* offsets   = counts + N;
    int* cursor    = offsets + (N + 1);
    int* edge_list = cursor + N;

    hipMemsetAsync(counts, 0, (size_t)N * sizeof(int), stream);
    hist_kernel<<<(E + 255) / 256, 256, 0, stream>>>(dst, counts);
    scan_kernel<<<1, 1024, 0, stream>>>(counts, offsets, cursor);
    scatter_kernel<<<(E + 255) / 256, 256, 0, stream>>>(dst, cursor, edge_list);

    edge_kernel<<<E, 256, 0, stream>>>(in_feat, src, dst,
                                       skw, dkw, skb, dkb,
                                       svw, dvw, svb, dvb,
                                       query, key_feat, value_feat, attn);

    node_kernel<<<N / 4, 256, 0, stream>>>(offsets, edge_list,
                                           in_feat, value_feat,
                                           node_w, node_b, ln_w, ln_b,
                                           attn, out);
}